// Round 1
// baseline (277.435 us; speedup 1.0000x reference)
//
#include <hip/hip_runtime.h>

#define T_LEN   262144
#define NTAG    128
#define L_CHUNK 64
#define B_BURN  32
#define N_CHUNK (T_LEN / L_CHUNK)      // 4096 chunks
#define WG_CHUNKS 4
#define N_WG    (N_CHUNK / WG_CHUNKS)  // 1024 workgroups

// ---------------------------------------------------------------------------
// Phase 1: parallel forward algorithm with burn-in chunks.
// alpha_t[j] = logsumexp_i(alpha_{t-1}[i] + trans[i,j]) + emit[t,j]
// Exp-domain: S[j] = sum_i exp(ahat[i]) * Q[i][j],  Q = exp(trans)
//             b[j] = log(S[j]) + emit[t,j];  m = max(b);  ahat = b - m;  dc = m
// logZ = sum_t dc_t + lse(ahat_{T-1} + etrans)
// Each 256-thread WG handles 4 chunks; wave w register-caches Q rows
// [32w,32w+32) and computes matvec partials for all 4 chunks; wave k owns
// chunk k's reduce/normalize step.
// ---------------------------------------------------------------------------
__global__ __launch_bounds__(256, 4) void crf_forward(
    const float* __restrict__ emit,
    const float* __restrict__ trans,
    const float* __restrict__ strans,
    const float* __restrict__ etrans,
    double* __restrict__ ws)
{
  const int w  = threadIdx.x >> 6;   // wave id 0..3
  const int l  = threadIdx.x & 63;   // lane
  const int j0 = 2 * l;              // this lane's two columns
  const int g  = blockIdx.x * WG_CHUNKS + w;  // chunk this wave reduces

  __shared__ float p_lds[WG_CHUNKS][NTAG];      // exp(ahat) per chunk
  __shared__ float s_stage[4][WG_CHUNKS][NTAG]; // matvec partials [wave][chunk][j]

  // --- register-cache Q slice: rows [32w, 32w+32), cols j0, j0+1 ---
  float2 Qr[32];
#pragma unroll
  for (int ii = 0; ii < 32; ++ii) {
    const float* tp = trans + (size_t)(32 * w + ii) * NTAG + j0;
    Qr[ii] = make_float2(__expf(tp[0]), __expf(tp[1]));
  }

  // --- init chunk state ---
  const int t0       = (g == 0) ? 1 : (g * L_CHUNK - B_BURN);
  const int accum_lo = g * L_CHUNK;
  const int accum_hi = g * L_CHUNK + L_CHUNK;
  float acc = 0.0f;
  float2 ahat;
  {
    float2 a0;
    if (g == 0) {
      a0.x = strans[j0]     + emit[j0];
      a0.y = strans[j0 + 1] + emit[j0 + 1];
      float m = fmaxf(a0.x, a0.y);
#pragma unroll
      for (int off = 1; off < 64; off <<= 1) m = fmaxf(m, __shfl_xor(m, off, 64));
      acc = m;                  // dc_0
      a0.x -= m; a0.y -= m;
    } else {
      a0 = make_float2(0.0f, 0.0f);  // uniform init, forgotten during burn-in
    }
    ahat = a0;
    p_lds[w][j0]     = __expf(a0.x);
    p_lds[w][j0 + 1] = __expf(a0.y);
  }
  __syncthreads();

  const int NSTEP = L_CHUNK + B_BURN;  // 96
  for (int s = 0; s < NSTEP; ++s) {
    const int t = t0 + s;

    // prefetch emit row for the chunk I reduce (independent of FMA phase)
    const float* ep = emit + (size_t)t * NTAG + j0;
    const float ex = ep[0];
    const float ey = ep[1];

    // --- FMA phase: partial matvec over my i-slice for all 4 chunks ---
#pragma unroll
    for (int k = 0; k < WG_CHUNKS; ++k) {
      const float* pk = &p_lds[k][32 * w];
      float sx = 0.0f, sy = 0.0f;
#pragma unroll
      for (int ii = 0; ii < 32; ii += 4) {
        const float4 p4 = *(const float4*)(pk + ii);  // LDS broadcast read
        sx = fmaf(p4.x, Qr[ii + 0].x, sx); sy = fmaf(p4.x, Qr[ii + 0].y, sy);
        sx = fmaf(p4.y, Qr[ii + 1].x, sx); sy = fmaf(p4.y, Qr[ii + 1].y, sy);
        sx = fmaf(p4.z, Qr[ii + 2].x, sx); sy = fmaf(p4.z, Qr[ii + 2].y, sy);
        sx = fmaf(p4.w, Qr[ii + 3].x, sx); sy = fmaf(p4.w, Qr[ii + 3].y, sy);
      }
      s_stage[w][k][j0]     = sx;
      s_stage[w][k][j0 + 1] = sy;
    }
    __syncthreads();

    // --- reduce phase: wave w owns chunk w ---
    {
      float2 v0 = *(const float2*)&s_stage[0][w][j0];
      float2 v1 = *(const float2*)&s_stage[1][w][j0];
      float2 v2 = *(const float2*)&s_stage[2][w][j0];
      float2 v3 = *(const float2*)&s_stage[3][w][j0];
      float sx = (v0.x + v1.x) + (v2.x + v3.x);
      float sy = (v0.y + v1.y) + (v2.y + v3.y);
      float bx = __logf(sx) + ex;
      float by = __logf(sy) + ey;
      float m = fmaxf(bx, by);
#pragma unroll
      for (int off = 1; off < 64; off <<= 1) m = fmaxf(m, __shfl_xor(m, off, 64));
      if (t >= accum_lo && t < accum_hi) acc += m;   // uniform per wave
      ahat.x = bx - m;
      ahat.y = by - m;
      p_lds[w][j0]     = __expf(ahat.x);
      p_lds[w][j0 + 1] = __expf(ahat.y);
    }
    __syncthreads();
  }

  // --- emit results ---
  if (l == 0) atomicAdd(&ws[0], (double)acc);
  if (g == N_CHUNK - 1) {
    // final lse(ahat + etrans); max(ahat)=0 so exp is safe
    float v = __expf(ahat.x + etrans[j0]) + __expf(ahat.y + etrans[j0 + 1]);
#pragma unroll
    for (int off = 1; off < 64; off <<= 1) v += __shfl_xor(v, off, 64);
    if (l == 0) atomicAdd(&ws[0], (double)__logf(v));
  }
}

// ---------------------------------------------------------------------------
// Phase 2: supervised path score (gather + reduce)
// ---------------------------------------------------------------------------
__global__ void crf_score(const float* __restrict__ emit,
                          const int* __restrict__ y,
                          const float* __restrict__ trans,
                          const float* __restrict__ strans,
                          const float* __restrict__ etrans,
                          double* __restrict__ ws)
{
  const int t = blockIdx.x * blockDim.x + threadIdx.x;
  float v = 0.0f;
  if (t < T_LEN - 1) {
    const int yt = y[t];
    const int yn = y[t + 1];
    v = trans[yt * NTAG + yn] + emit[(size_t)t * NTAG + yt];
    if (t == 0) {
      const int ylast = y[T_LEN - 1];
      v += strans[y[0]] + etrans[ylast] + emit[(size_t)(T_LEN - 1) * NTAG + ylast];
    }
  }
#pragma unroll
  for (int off = 1; off < 64; off <<= 1) v += __shfl_xor(v, off, 64);
  if ((threadIdx.x & 63) == 0) atomicAdd(&ws[1], (double)v);
}

__global__ void crf_final(const double* __restrict__ ws, float* __restrict__ out)
{
  out[0] = (float)(ws[0] - ws[1]);
}

// ---------------------------------------------------------------------------
extern "C" void kernel_launch(void* const* d_in, const int* in_sizes, int n_in,
                              void* d_out, int out_size, void* d_ws, size_t ws_size,
                              hipStream_t stream)
{
  const float* emit   = (const float*)d_in[0];
  const int*   y      = (const int*)d_in[1];
  const float* trans  = (const float*)d_in[2];
  const float* strans = (const float*)d_in[3];
  const float* etrans = (const float*)d_in[4];
  float*  out = (float*)d_out;
  double* ws  = (double*)d_ws;

  hipMemsetAsync(ws, 0, 2 * sizeof(double), stream);
  crf_score<<<dim3((T_LEN + 255) / 256), dim3(256), 0, stream>>>(
      emit, y, trans, strans, etrans, ws);
  crf_forward<<<dim3(N_WG), dim3(256), 0, stream>>>(
      emit, trans, strans, etrans, ws);
  crf_final<<<dim3(1), dim3(1), 0, stream>>>(ws, out);
}

// Round 2
// 88.599 us; speedup vs baseline: 3.1314x; 3.1314x over previous
//
#include <hip/hip_runtime.h>

typedef _Float16 f16x4 __attribute__((ext_vector_type(4)));
typedef float    f32x4 __attribute__((ext_vector_type(4)));

#define T_LEN   262144
#define NTAG    128
#define LCH     64      // chunk length
#define BURN    32      // burn-in steps
#define NSTEP   96      // LCH + BURN
#define MCH     16      // chunks per WG (MFMA M dim)
#define NFWD    256     // forward WGs (4096 chunks / 16)
#define NSCORE  256     // score WGs

// ---------------------------------------------------------------------------
// Forward algorithm on MFMA. Per WG: 16 chunks. Per step, the 4 waves compute
// R[tag_out][chunk] = sum_in Q[in][out] * p[chunk][in] as A(=Q^T frag, regs) x
// B(=p frag, LDS). C/D layout (col=lane&15=chunk, row=(lane>>4)*4+r=tag)
// exactly matches the B-frag k-pattern, so normalize->exp->pack->pb write
// needs no cross-lane moves. logZ = sum m_t + log(sum p_final*exp(etrans)).
// ---------------------------------------------------------------------------
__global__ __launch_bounds__(256) void crf_fused(
    const float* __restrict__ emit, const int* __restrict__ y,
    const float* __restrict__ trans, const float* __restrict__ strans,
    const float* __restrict__ etrans, double* __restrict__ ws)
{
  if (blockIdx.x >= NFWD) {
    // ---- score path (independent blocks) ----
    __shared__ float sred[4];
    int idx0 = (blockIdx.x - NFWD) * 256 + threadIdx.x;
    float v = 0.f;
    for (int t = idx0; t < T_LEN - 1; t += NSCORE * 256) {
      int yt = y[t], yn = y[t + 1];
      v += trans[yt * NTAG + yn] + emit[(size_t)t * NTAG + yt];
    }
    if (idx0 == 0) {
      int yl = y[T_LEN - 1];
      v += strans[y[0]] + etrans[yl] + emit[(size_t)(T_LEN - 1) * NTAG + yl];
    }
#pragma unroll
    for (int off = 1; off < 64; off <<= 1) v += __shfl_xor(v, off, 64);
    if ((threadIdx.x & 63) == 0) sred[threadIdx.x >> 6] = v;
    __syncthreads();
    if (threadIdx.x == 0)
      atomicAdd(&ws[1], (double)(sred[0] + sred[1] + sred[2] + sred[3]));
    return;
  }

  // ---- forward path ----
  __shared__ uint2 pb[8][64];         // B fragments: [ktile][lane] = 4 f16
  __shared__ float emlds[MCH][132];   // staged emit rows (pad->2-way banks max)
  __shared__ float wmaxT[MCH][4];     // per-wave chunk maxes

  const int tid   = threadIdx.x;
  const int w     = tid >> 6;         // wave 0..3 (owns out-tags [32w,32w+32))
  const int l     = tid & 63;
  const int chunk = l & 15;           // fragment column = chunk
  const int grp   = l >> 4;           // lane group 0..3
  const int g0    = blockIdx.x * MCH;
  const int gc    = g0 + chunk;       // this lane's global chunk
  const bool lane_g0 = (gc == 0);

  // --- one-time: Q^T fragments in registers, qa[mt][kt], fp16 ---
  f16x4 qa[2][8];
#pragma unroll
  for (int mt = 0; mt < 2; ++mt) {
    const int out = 32 * w + 16 * mt + chunk;   // A row = out-tag
#pragma unroll
    for (int kt = 0; kt < 8; ++kt) {
      f16x4 a;
#pragma unroll
      for (int j = 0; j < 4; ++j)
        a[j] = (_Float16)__expf(trans[(size_t)(16 * kt + 4 * grp + j) * NTAG + out]);
      qa[mt][kt] = a;
    }
  }

  // emit staging roles: thread stages row c_row, cols [4c16,4c16+4) and +64
  const int c_row = tid >> 4;
  const int c16   = tid & 15;
  // emit row for matvec iteration i (produces state at time t_c(i+1))
  auto erow = [&](int i) -> int {
    int gcr = g0 + c_row;
    return (gcr == 0) ? (i + 1) : (gcr * LCH - BURN + i);
  };

  // --- prologue: stage emit rows for iter 0 ---
  {
    const float* rp = emit + (size_t)erow(0) * NTAG;
    float4 e0 = *(const float4*)(rp + 4 * c16);
    float4 e1 = *(const float4*)(rp + 4 * c16 + 64);
    *(float4*)&emlds[c_row][4 * c16]      = e0;
    *(float4*)&emlds[c_row][4 * c16 + 64] = e1;
  }

  // --- init b: chunk 0 gets exact alpha_0 = strans + emit[0]; others 0 ---
  float b[2][4];
#pragma unroll
  for (int mt = 0; mt < 2; ++mt)
#pragma unroll
    for (int r = 0; r < 4; ++r) b[mt][r] = 0.f;
  if (lane_g0) {
#pragma unroll
    for (int mt = 0; mt < 2; ++mt)
#pragma unroll
      for (int r = 0; r < 4; ++r) {
        int tag = 32 * w + 16 * mt + 4 * grp + r;
        b[mt][r] = strans[tag] + emit[tag];
      }
  }
  // normalize init state
  float vm = b[0][0];
#pragma unroll
  for (int r = 1; r < 4; ++r) vm = fmaxf(vm, b[0][r]);
#pragma unroll
  for (int r = 0; r < 4; ++r) vm = fmaxf(vm, b[1][r]);
  vm = fmaxf(vm, __shfl_xor(vm, 16, 64));
  vm = fmaxf(vm, __shfl_xor(vm, 32, 64));
  if (grp == 0) wmaxT[chunk][w] = vm;
  __syncthreads();
  float4 wm0 = *(const float4*)&wmaxT[chunk][0];
  float m = fmaxf(fmaxf(wm0.x, wm0.y), fmaxf(wm0.z, wm0.w));
  float acc = lane_g0 ? m : 0.f;      // dc_0 for global chunk 0
#pragma unroll
  for (int mt = 0; mt < 2; ++mt) {
    union { uint2 u; f16x4 h; } pk;
#pragma unroll
    for (int r = 0; r < 4; ++r) pk.h[r] = (_Float16)__expf(b[mt][r] - m);
    pb[2 * w + mt][l] = pk.u;
  }
  __syncthreads();

  // --- main loop: 96 matvec steps ---
  float4 pf0, pf1;
  for (int s = 0; s < NSTEP; ++s) {
    // issue emit prefetch for next iter (consumed in phase 3)
    if (s < NSTEP - 1) {
      const float* rp = emit + (size_t)erow(s + 1) * NTAG;
      pf0 = *(const float4*)(rp + 4 * c16);
      pf1 = *(const float4*)(rp + 4 * c16 + 64);
    }
    // phase 1: MFMA  (A = Q^T frags, B = p frags from LDS)
    f32x4 c0 = {0.f, 0.f, 0.f, 0.f};
    f32x4 c1 = {0.f, 0.f, 0.f, 0.f};
#pragma unroll
    for (int kt = 0; kt < 8; ++kt) {
      union { uint2 u; f16x4 h; } bf;
      bf.u = pb[kt][l];
      c0 = __builtin_amdgcn_mfma_f32_16x16x16f16(qa[0][kt], bf.h, c0, 0, 0, 0);
      c1 = __builtin_amdgcn_mfma_f32_16x16x16f16(qa[1][kt], bf.h, c1, 0, 0, 0);
    }
    // phase 2: b = log(S) + emit ; wave-local max
    float4 em0 = *(const float4*)&emlds[chunk][32 * w + 4 * grp];
    float4 em1 = *(const float4*)&emlds[chunk][32 * w + 16 + 4 * grp];
    b[0][0] = __logf(c0[0]) + em0.x;
    b[0][1] = __logf(c0[1]) + em0.y;
    b[0][2] = __logf(c0[2]) + em0.z;
    b[0][3] = __logf(c0[3]) + em0.w;
    b[1][0] = __logf(c1[0]) + em1.x;
    b[1][1] = __logf(c1[1]) + em1.y;
    b[1][2] = __logf(c1[2]) + em1.z;
    b[1][3] = __logf(c1[3]) + em1.w;
    vm = b[0][0];
#pragma unroll
    for (int r = 1; r < 4; ++r) vm = fmaxf(vm, b[0][r]);
#pragma unroll
    for (int r = 0; r < 4; ++r) vm = fmaxf(vm, b[1][r]);
    vm = fmaxf(vm, __shfl_xor(vm, 16, 64));
    vm = fmaxf(vm, __shfl_xor(vm, 32, 64));
    if (grp == 0) wmaxT[chunk][w] = vm;
    __syncthreads();   // B: wmax visible
    // phase 3: cross-wave max, dc accumulate, p = exp(b-m), pack, write pb
    float4 wm = *(const float4*)&wmaxT[chunk][0];
    m = fmaxf(fmaxf(wm.x, wm.y), fmaxf(wm.z, wm.w));
    {
      int tstate = lane_g0 ? (s + 1) : (gc * LCH - BURN + s);
      if (tstate >= gc * LCH && tstate < gc * LCH + LCH) acc += m;
    }
    float pf[2][4];
#pragma unroll
    for (int mt = 0; mt < 2; ++mt) {
      union { uint2 u; f16x4 h; } pk;
#pragma unroll
      for (int r = 0; r < 4; ++r) {
        pf[mt][r] = __expf(b[mt][r] - m);
        pk.h[r]   = (_Float16)pf[mt][r];
      }
      pb[2 * w + mt][l] = pk.u;
    }
    // final-state LSE contribution (last global chunk, after last normalize)
    if (s == NSTEP - 1 && blockIdx.x == NFWD - 1 && chunk == 15) {
      float lv = 0.f;
#pragma unroll
      for (int mt = 0; mt < 2; ++mt)
#pragma unroll
        for (int r = 0; r < 4; ++r)
          lv += pf[mt][r] * __expf(etrans[32 * w + 16 * mt + 4 * grp + r]);
      atomicAdd(&ws[2], (double)lv);
    }
    // write next iter's emit rows
    if (s < NSTEP - 1) {
      *(float4*)&emlds[c_row][4 * c16]      = pf0;
      *(float4*)&emlds[c_row][4 * c16 + 64] = pf1;
    }
    __syncthreads();   // A: pb + emit visible
  }

  // --- reduce per-chunk dc sums: lanes 0..15 of wave 0 hold chunk accs ---
  if (w == 0) {
    float a = acc;
#pragma unroll
    for (int off = 1; off < 16; off <<= 1) a += __shfl_xor(a, off, 64);
    if (l == 0) atomicAdd(&ws[0], (double)a);
  }
}

__global__ void crf_final(const double* __restrict__ ws, float* __restrict__ out)
{
  out[0] = (float)(ws[0] + log(ws[2]) - ws[1]);
}

// ---------------------------------------------------------------------------
extern "C" void kernel_launch(void* const* d_in, const int* in_sizes, int n_in,
                              void* d_out, int out_size, void* d_ws, size_t ws_size,
                              hipStream_t stream)
{
  const float* emit   = (const float*)d_in[0];
  const int*   y      = (const int*)d_in[1];
  const float* trans  = (const float*)d_in[2];
  const float* strans = (const float*)d_in[3];
  const float* etrans = (const float*)d_in[4];
  float*  out = (float*)d_out;
  double* ws  = (double*)d_ws;

  hipMemsetAsync(ws, 0, 3 * sizeof(double), stream);
  crf_fused<<<dim3(NFWD + NSCORE), dim3(256), 0, stream>>>(
      emit, y, trans, strans, etrans, ws);
  crf_final<<<dim3(1), dim3(1), 0, stream>>>(ws, out);
}